// Round 2
// baseline (211.362 us; speedup 1.0000x reference)
//
#include <hip/hip_runtime.h>

// Batched Kalman filter, algebraically reduced:
//   B   = H @ phi                   (8x16,  per-block precompute)
//   Sc  = H diag(Q) H^T + diag(R)   (8x8,   per-block precompute)
//   QHT[r][m] = Q[r] * H[m][r]      (16x8,  per-block precompute)
//   T   = P0 @ B^T                  (16x8 per element)
//   S   = B @ T + Sc                (8x8, SPD)
//   y   = z - B @ x0
//   w   = S^-1 y                    (lane-parallel GE, no pivoting)
//   x_new = phi@x0 + phi@(T w) + QHT @ w
//   out = C @ x_new
// P_pred is never formed. 8 threads/element (thread i owns rows i, i+8),
// 32 elements per 256-thread block. Only T goes through LDS cross-thread;
// t-hat and x_new are distributed via 8-wide shuffles.

#define QFMA(ACC, OFF, A, V) { ACC[(OFF)+0] += (A)*(V).x; ACC[(OFF)+1] += (A)*(V).y; ACC[(OFF)+2] += (A)*(V).z; ACC[(OFF)+3] += (A)*(V).w; }
#define TS 132  // per-element float stride of T buffer (4*33: odd quad -> bijective bank spread)

__global__ __launch_bounds__(256, 6) void kalman_fused2(
    const float* __restrict__ z,
    const float* __restrict__ x0,
    const float* __restrict__ P0,
    const float* __restrict__ phi,
    const float* __restrict__ Hm,
    const float* __restrict__ Cm,
    const float* __restrict__ Qd,
    const float* __restrict__ Rd,
    float* __restrict__ out,
    int bs)
{
    __shared__ __align__(16) float phiS[16 * 20];  // phi rows, stride 20 (conflict-free quads)
    __shared__ __align__(16) float BnS[8 * 20];    // B rows, stride 20
    __shared__ __align__(16) float BTS[16 * 8];    // BT[k][m] = B[m][k] (wave-uniform reads)
    __shared__ __align__(16) float QHTS[16 * 12];  // QHT rows, stride 12
    __shared__ __align__(16) float ScS[8 * 8];     // Sc rows, stride 8 (2-way = free)
    __shared__ __align__(16) float CsS[8 * 20];    // C rows, stride 20
    __shared__ __align__(16) float x0S[32 * 20];   // per-element x0, stride 20
    __shared__ __align__(16) float Tb[32 * TS];    // per-element T (16 rows x 8, row stride 8)

    const int tid = threadIdx.x;
    const int e = tid >> 3;      // element in block (0..31)
    const int i = tid & 7;       // lane in element (0..7)
    long b = (long)blockIdx.x * 32 + e;
    const bool valid = (b < (long)bs);
    if (!valid) b = (long)bs - 1;

    // ---- prologue: stage phi, derived matrices (reads global H/phi, L2-hot) ----
    {
        const int r = tid >> 4, c = tid & 15;
        phiS[r * 20 + c] = phi[tid];
    }
    if (tid < 128) {
        const int m = tid >> 4, k = tid & 15;
        float bv = 0.f;
#pragma unroll
        for (int j = 0; j < 16; ++j) bv += Hm[m * 16 + j] * phi[j * 16 + k];
        BnS[m * 20 + k] = bv;
        BTS[k * 8 + m] = bv;
        const int k2 = tid >> 3, m2 = tid & 7;
        QHTS[k2 * 12 + m2] = Qd[k2] * Hm[m2 * 16 + k2];
        CsS[(tid >> 4) * 20 + (tid & 15)] = Cm[tid];
    }
    if (tid < 64) {
        const int i2 = tid >> 3, j2 = tid & 7;
        float sc = (i2 == j2) ? Rd[i2] : 0.f;
#pragma unroll
        for (int k = 0; k < 16; ++k) sc += Hm[i2 * 16 + k] * Qd[k] * Hm[j2 * 16 + k];
        ScS[i2 * 8 + j2] = sc;
    }
    // stage x0
    x0S[e * 20 + i]     = x0[b * 16 + i];
    x0S[e * 20 + i + 8] = x0[b * 16 + i + 8];
    // z early (hide latency)
    float yv = z[b * 8 + i];

    // ---- load P0 rows i, i+8 ----
    float p0r[16], p1r[16];
    {
        const float4* P0v = reinterpret_cast<const float4*>(P0 + (size_t)b * 256);
#pragma unroll
        for (int q = 0; q < 4; ++q) {
            const float4 A = P0v[i * 4 + q];
            const float4 Bq = P0v[(i + 8) * 4 + q];
            p0r[4*q+0] = A.x;  p0r[4*q+1] = A.y;  p0r[4*q+2] = A.z;  p0r[4*q+3] = A.w;
            p1r[4*q+0] = Bq.x; p1r[4*q+1] = Bq.y; p1r[4*q+2] = Bq.z; p1r[4*q+3] = Bq.w;
        }
    }

    __syncthreads();  // constants + x0 staged

    // ---- T rows: T[r][m] = sum_k P0[r][k] * BT[k][m] ----
    float t0[8], t1[8];
#pragma unroll
    for (int m = 0; m < 8; ++m) { t0[m] = 0.f; t1[m] = 0.f; }
#pragma unroll
    for (int k = 0; k < 16; ++k) {
        const float4 b0 = *reinterpret_cast<const float4*>(&BTS[k * 8 + 0]);
        const float4 b1 = *reinterpret_cast<const float4*>(&BTS[k * 8 + 4]);
        const float a0 = p0r[k], a1 = p1r[k];
        QFMA(t0, 0, a0, b0) QFMA(t0, 4, a0, b1)
        QFMA(t1, 0, a1, b0) QFMA(t1, 4, a1, b1)
    }
    // stage T (row stride 8, element stride TS)
    *reinterpret_cast<float4*>(&Tb[e * TS + i * 8 + 0]) = make_float4(t0[0], t0[1], t0[2], t0[3]);
    *reinterpret_cast<float4*>(&Tb[e * TS + i * 8 + 4]) = make_float4(t0[4], t0[5], t0[6], t0[7]);
    *reinterpret_cast<float4*>(&Tb[e * TS + (i + 8) * 8 + 0]) = make_float4(t1[0], t1[1], t1[2], t1[3]);
    *reinterpret_cast<float4*>(&Tb[e * TS + (i + 8) * 8 + 4]) = make_float4(t1[4], t1[5], t1[6], t1[7]);
    __syncthreads();  // T staged

    // ---- B row i -> regs (used for S row and y) ----
    float br[16];
#pragma unroll
    for (int q = 0; q < 4; ++q) {
        const float4 A = *reinterpret_cast<const float4*>(&BnS[i * 20 + 4 * q]);
        br[4*q+0] = A.x; br[4*q+1] = A.y; br[4*q+2] = A.z; br[4*q+3] = A.w;
    }

    // ---- S row i = Sc[i,:] + B[i,:] @ T ----
    float s[8];
    {
        const float4 c0 = *reinterpret_cast<const float4*>(&ScS[i * 8 + 0]);
        const float4 c1 = *reinterpret_cast<const float4*>(&ScS[i * 8 + 4]);
        s[0]=c0.x; s[1]=c0.y; s[2]=c0.z; s[3]=c0.w; s[4]=c1.x; s[5]=c1.y; s[6]=c1.z; s[7]=c1.w;
    }
#pragma unroll
    for (int j = 0; j < 16; ++j) {
        const float4 ta = *reinterpret_cast<const float4*>(&Tb[e * TS + j * 8 + 0]);
        const float4 tb = *reinterpret_cast<const float4*>(&Tb[e * TS + j * 8 + 4]);
        const float bij = br[j];
        QFMA(s, 0, bij, ta) QFMA(s, 4, bij, tb)
    }

    // ---- y_i = z_i - B[i,:] @ x0 ;  x_pred rows i,i+8 = phi rows @ x0 ----
    float xp0 = 0.f, xp1 = 0.f;
#pragma unroll
    for (int q = 0; q < 4; ++q) {
        const float4 X  = *reinterpret_cast<const float4*>(&x0S[e * 20 + 4 * q]);
        yv  -= br[4*q+0]*X.x + br[4*q+1]*X.y + br[4*q+2]*X.z + br[4*q+3]*X.w;
        const float4 F0 = *reinterpret_cast<const float4*>(&phiS[i * 20 + 4 * q]);
        const float4 F1 = *reinterpret_cast<const float4*>(&phiS[(i + 8) * 20 + 4 * q]);
        xp0 += F0.x*X.x + F0.y*X.y + F0.z*X.z + F0.w*X.w;
        xp1 += F1.x*X.x + F1.y*X.y + F1.z*X.z + F1.w*X.w;
    }

    // ---- solve S w = y : lane-parallel GE (S SPD, no pivoting) ----
#pragma unroll
    for (int k = 0; k < 7; ++k) {
        float pr[8];
#pragma unroll
        for (int j = 0; j < 8; ++j) pr[j] = __shfl(s[j], k, 8);
        const float py = __shfl(yv, k, 8);
        if (i > k) {
            const float f = s[k] / pr[k];
#pragma unroll
            for (int j = 0; j < 8; ++j) s[j] -= f * pr[j];
            yv -= f * py;
        }
    }
    float w[8];
#pragma unroll
    for (int k = 7; k >= 0; --k) {
        const float num = __shfl(yv, k, 8);
        const float den = __shfl(s[k], k, 8);
        const float wk = num / den;
        w[k] = wk;
        if (i < k) yv -= s[k] * wk;
    }

    // ---- t-hat rows: th[r] = T[r,:] @ w (own rows, in registers) ----
    float th0 = 0.f, th1 = 0.f;
#pragma unroll
    for (int m = 0; m < 8; ++m) { th0 += t0[m] * w[m]; th1 += t1[m] * w[m]; }

    // ---- gather full t-hat via shuffles ----
    float tv[16];
#pragma unroll
    for (int j = 0; j < 8; ++j) {
        tv[j]     = __shfl(th0, j, 8);
        tv[j + 8] = __shfl(th1, j, 8);
    }

    // ---- x_new rows i,i+8 = xp + phi[r,:] @ tv + QHT[r,:] @ w ----
    float xn0 = xp0, xn1 = xp1;
    {
        const float4 qa0 = *reinterpret_cast<const float4*>(&QHTS[i * 12 + 0]);
        const float4 qa1 = *reinterpret_cast<const float4*>(&QHTS[i * 12 + 4]);
        const float4 qb0 = *reinterpret_cast<const float4*>(&QHTS[(i + 8) * 12 + 0]);
        const float4 qb1 = *reinterpret_cast<const float4*>(&QHTS[(i + 8) * 12 + 4]);
        xn0 += qa0.x*w[0] + qa0.y*w[1] + qa0.z*w[2] + qa0.w*w[3]
             + qa1.x*w[4] + qa1.y*w[5] + qa1.z*w[6] + qa1.w*w[7];
        xn1 += qb0.x*w[0] + qb0.y*w[1] + qb0.z*w[2] + qb0.w*w[3]
             + qb1.x*w[4] + qb1.y*w[5] + qb1.z*w[6] + qb1.w*w[7];
    }
#pragma unroll
    for (int q = 0; q < 4; ++q) {
        const float4 F0 = *reinterpret_cast<const float4*>(&phiS[i * 20 + 4 * q]);
        const float4 F1 = *reinterpret_cast<const float4*>(&phiS[(i + 8) * 20 + 4 * q]);
        xn0 += F0.x*tv[4*q+0] + F0.y*tv[4*q+1] + F0.z*tv[4*q+2] + F0.w*tv[4*q+3];
        xn1 += F1.x*tv[4*q+0] + F1.y*tv[4*q+1] + F1.z*tv[4*q+2] + F1.w*tv[4*q+3];
    }

    // ---- gather x_new, out[b][i] = C[i,:] @ x_new ----
    float xv[16];
#pragma unroll
    for (int j = 0; j < 8; ++j) {
        xv[j]     = __shfl(xn0, j, 8);
        xv[j + 8] = __shfl(xn1, j, 8);
    }
    float o = 0.f;
#pragma unroll
    for (int q = 0; q < 4; ++q) {
        const float4 A = *reinterpret_cast<const float4*>(&CsS[i * 20 + 4 * q]);
        o += A.x*xv[4*q+0] + A.y*xv[4*q+1] + A.z*xv[4*q+2] + A.w*xv[4*q+3];
    }
    if (valid) out[b * 8 + i] = o;
}

extern "C" void kernel_launch(void* const* d_in, const int* in_sizes, int n_in,
                              void* d_out, int out_size, void* d_ws, size_t ws_size,
                              hipStream_t stream)
{
    const float* z   = (const float*)d_in[0];
    const float* x0  = (const float*)d_in[1];
    const float* P0  = (const float*)d_in[2];
    const float* phi = (const float*)d_in[3];
    const float* H   = (const float*)d_in[4];
    const float* C   = (const float*)d_in[5];
    const float* Qd  = (const float*)d_in[6];
    const float* Rd  = (const float*)d_in[7];
    float* out = (float*)d_out;

    const int bs = in_sizes[0] / 8;          // z is [bs, 8]
    const int blocks = (bs + 31) / 32;       // 32 elements per block
    hipLaunchKernelGGL(kalman_fused2, dim3(blocks), dim3(256), 0, stream,
                       z, x0, P0, phi, H, C, Qd, Rd, out, bs);
}

// Round 3
// 86.986 us; speedup vs baseline: 2.4298x; 2.4298x over previous
//
#include <hip/hip_runtime.h>

// Batched Kalman filter, algebraically reduced (P_pred never formed):
//   B   = H @ phi                   (8x16,  per-block precompute from LDS)
//   Sc  = H diag(Q) H^T + diag(R)   (8x8,   per-block precompute)
//   QHT[r][m] = Q[r] * H[m][r]      (16x8,  per-block precompute)
//   T   = P0 @ B^T                  (16x8 per element)
//   S   = B @ T + Sc                (8x8, SPD)
//   y   = z - B @ x0
//   w   = S^-1 y                    (lane-parallel GE, no pivoting)
//   x_new = phi@x0 + phi@(T w) + QHT @ w
//   out = C @ x_new
// 8 threads/element (thread i owns rows i, i+8), 32 elements per 256-thread
// block. Only T crosses threads via LDS; t-hat/x_new gathered by 8-wide shfl.
//
// NOTE: plain __launch_bounds__(256). Round-2's (256,6) min-waves hint forced
// VGPR=40 -> ~470 MB/dispatch of scratch spill traffic (dur 147->211us).
// Natural allocation (~80 VGPR, round 1) spills nothing; LDS (~24 KB) then
// allows 6 blocks/CU on its own.

#define QFMA(ACC, OFF, A, V) { ACC[(OFF)+0] += (A)*(V).x; ACC[(OFF)+1] += (A)*(V).y; ACC[(OFF)+2] += (A)*(V).z; ACC[(OFF)+3] += (A)*(V).w; }
#define TS 132  // per-element float stride of T buffer (4*33: odd quad -> bijective bank spread)

__global__ __launch_bounds__(256) void kalman_fused3(
    const float* __restrict__ z,
    const float* __restrict__ x0,
    const float* __restrict__ P0,
    const float* __restrict__ phi,
    const float* __restrict__ Hm,
    const float* __restrict__ Cm,
    const float* __restrict__ Qd,
    const float* __restrict__ Rd,
    float* __restrict__ out,
    int bs)
{
    __shared__ __align__(16) float phiS[16 * 20];  // phi rows, stride 20
    __shared__ __align__(16) float HnS[8 * 20];    // H rows, stride 20
    __shared__ __align__(16) float BnS[8 * 20];    // B rows, stride 20
    __shared__ __align__(16) float BTS[16 * 8];    // BT[k][m] = B[m][k] (broadcast reads)
    __shared__ __align__(16) float QHTS[16 * 12];  // QHT rows, stride 12
    __shared__ __align__(16) float ScS[8 * 8];     // Sc rows, stride 8
    __shared__ __align__(16) float CsS[8 * 20];    // C rows, stride 20
    __shared__            float QdS[16];
    __shared__            float RdS[8];
    __shared__ __align__(16) float x0S[32 * 20];   // per-element x0, stride 20
    __shared__ __align__(16) float Tb[32 * TS];    // per-element T (16 rows x 8, row stride 8)

    const int tid = threadIdx.x;
    const int e = tid >> 3;      // element in block (0..31)
    const int i = tid & 7;       // lane in element (0..7)
    long b = (long)blockIdx.x * 32 + e;
    const bool valid = (b < (long)bs);
    if (!valid) b = (long)bs - 1;

    // ---- stage raw constants (coalesced), x0, z; issue P0 loads ----
    {
        const int r = tid >> 4, c = tid & 15;
        phiS[r * 20 + c] = phi[tid];
    }
    if (tid < 128) {
        const int m = tid >> 4, k = tid & 15;
        HnS[m * 20 + k] = Hm[tid];
        CsS[m * 20 + k] = Cm[tid];
    }
    if (tid < 16) QdS[tid] = Qd[tid];
    if (tid < 8)  RdS[tid] = Rd[tid];
    x0S[e * 20 + i]     = x0[b * 16 + i];
    x0S[e * 20 + i + 8] = x0[b * 16 + i + 8];
    float yv = z[b * 8 + i];

    // P0 rows i and i+8 as 8 float4s (live across both barriers; consumed once)
    float4 Pq[8];
    {
        const float4* P0v = reinterpret_cast<const float4*>(P0 + (size_t)b * 256);
#pragma unroll
        for (int q = 0; q < 4; ++q) {
            Pq[q]     = P0v[i * 4 + q];
            Pq[q + 4] = P0v[(i + 8) * 4 + q];
        }
    }
    __syncthreads();  // raw constants staged

    // ---- derived per-block matrices (from LDS, conflict-free) ----
    if (tid < 128) {
        const int m = tid >> 4, k = tid & 15;
        float bv = 0.f;
#pragma unroll
        for (int j = 0; j < 16; ++j) bv += HnS[m * 20 + j] * phiS[j * 20 + k];
        BnS[m * 20 + k] = bv;
        BTS[k * 8 + m] = bv;
        const int k2 = tid >> 3, m2 = tid & 7;
        QHTS[k2 * 12 + m2] = QdS[k2] * HnS[m2 * 20 + k2];
    }
    if (tid < 64) {
        const int i2 = tid >> 3, j2 = tid & 7;
        float sc = (i2 == j2) ? RdS[i2] : 0.f;
#pragma unroll
        for (int k = 0; k < 16; ++k) sc += HnS[i2 * 20 + k] * QdS[k] * HnS[j2 * 20 + k];
        ScS[i2 * 8 + j2] = sc;
    }
    __syncthreads();  // derived staged

    // ---- T rows: T[r][m] = sum_k P0[r][k] * BT[k][m] (stream Pq -> acc) ----
    float t0[8], t1[8];
#pragma unroll
    for (int m = 0; m < 8; ++m) { t0[m] = 0.f; t1[m] = 0.f; }
#pragma unroll
    for (int q = 0; q < 4; ++q) {
        const float4 A = Pq[q], B4 = Pq[q + 4];
        const float a[4] = {A.x, A.y, A.z, A.w};
        const float c[4] = {B4.x, B4.y, B4.z, B4.w};
#pragma unroll
        for (int kk = 0; kk < 4; ++kk) {
            const int k = 4 * q + kk;
            const float4 b0 = *reinterpret_cast<const float4*>(&BTS[k * 8 + 0]);
            const float4 b1 = *reinterpret_cast<const float4*>(&BTS[k * 8 + 4]);
            QFMA(t0, 0, a[kk], b0) QFMA(t0, 4, a[kk], b1)
            QFMA(t1, 0, c[kk], b0) QFMA(t1, 4, c[kk], b1)
        }
    }
    // stage T (row stride 8, element stride TS)
    *reinterpret_cast<float4*>(&Tb[e * TS + i * 8 + 0]) = make_float4(t0[0], t0[1], t0[2], t0[3]);
    *reinterpret_cast<float4*>(&Tb[e * TS + i * 8 + 4]) = make_float4(t0[4], t0[5], t0[6], t0[7]);
    *reinterpret_cast<float4*>(&Tb[e * TS + (i + 8) * 8 + 0]) = make_float4(t1[0], t1[1], t1[2], t1[3]);
    *reinterpret_cast<float4*>(&Tb[e * TS + (i + 8) * 8 + 4]) = make_float4(t1[4], t1[5], t1[6], t1[7]);
    __syncthreads();  // T staged

    // ---- B row i -> regs ----
    float br[16];
#pragma unroll
    for (int q = 0; q < 4; ++q) {
        const float4 A = *reinterpret_cast<const float4*>(&BnS[i * 20 + 4 * q]);
        br[4*q+0] = A.x; br[4*q+1] = A.y; br[4*q+2] = A.z; br[4*q+3] = A.w;
    }

    // ---- S row i = Sc[i,:] + B[i,:] @ T ----
    float s[8];
    {
        const float4 c0 = *reinterpret_cast<const float4*>(&ScS[i * 8 + 0]);
        const float4 c1 = *reinterpret_cast<const float4*>(&ScS[i * 8 + 4]);
        s[0]=c0.x; s[1]=c0.y; s[2]=c0.z; s[3]=c0.w; s[4]=c1.x; s[5]=c1.y; s[6]=c1.z; s[7]=c1.w;
    }
#pragma unroll
    for (int j = 0; j < 16; ++j) {
        const float4 ta = *reinterpret_cast<const float4*>(&Tb[e * TS + j * 8 + 0]);
        const float4 tb = *reinterpret_cast<const float4*>(&Tb[e * TS + j * 8 + 4]);
        const float bij = br[j];
        QFMA(s, 0, bij, ta) QFMA(s, 4, bij, tb)
    }

    // ---- y_i = z_i - B[i,:] @ x0 ; x_pred rows = phi rows @ x0 ----
    float xp0 = 0.f, xp1 = 0.f;
#pragma unroll
    for (int q = 0; q < 4; ++q) {
        const float4 X  = *reinterpret_cast<const float4*>(&x0S[e * 20 + 4 * q]);
        yv  -= br[4*q+0]*X.x + br[4*q+1]*X.y + br[4*q+2]*X.z + br[4*q+3]*X.w;
        const float4 F0 = *reinterpret_cast<const float4*>(&phiS[i * 20 + 4 * q]);
        const float4 F1 = *reinterpret_cast<const float4*>(&phiS[(i + 8) * 20 + 4 * q]);
        xp0 += F0.x*X.x + F0.y*X.y + F0.z*X.z + F0.w*X.w;
        xp1 += F1.x*X.x + F1.y*X.y + F1.z*X.z + F1.w*X.w;
    }

    // ---- solve S w = y : lane-parallel GE (S SPD, no pivoting) ----
#pragma unroll
    for (int k = 0; k < 7; ++k) {
        float pr[8];
#pragma unroll
        for (int j = 0; j < 8; ++j) pr[j] = __shfl(s[j], k, 8);
        const float py = __shfl(yv, k, 8);
        if (i > k) {
            const float f = s[k] / pr[k];
#pragma unroll
            for (int j = 0; j < 8; ++j) s[j] -= f * pr[j];
            yv -= f * py;
        }
    }
    float w[8];
#pragma unroll
    for (int k = 7; k >= 0; --k) {
        const float num = __shfl(yv, k, 8);
        const float den = __shfl(s[k], k, 8);
        const float wk = num / den;
        w[k] = wk;
        if (i < k) yv -= s[k] * wk;
    }

    // ---- t-hat rows (own rows, registers) ----
    float th0 = 0.f, th1 = 0.f;
#pragma unroll
    for (int m = 0; m < 8; ++m) { th0 += t0[m] * w[m]; th1 += t1[m] * w[m]; }

    // ---- gather full t-hat via shuffles ----
    float tv[16];
#pragma unroll
    for (int j = 0; j < 8; ++j) {
        tv[j]     = __shfl(th0, j, 8);
        tv[j + 8] = __shfl(th1, j, 8);
    }

    // ---- x_new rows i,i+8 = xp + phi[r,:] @ tv + QHT[r,:] @ w ----
    float xn0 = xp0, xn1 = xp1;
    {
        const float4 qa0 = *reinterpret_cast<const float4*>(&QHTS[i * 12 + 0]);
        const float4 qa1 = *reinterpret_cast<const float4*>(&QHTS[i * 12 + 4]);
        const float4 qb0 = *reinterpret_cast<const float4*>(&QHTS[(i + 8) * 12 + 0]);
        const float4 qb1 = *reinterpret_cast<const float4*>(&QHTS[(i + 8) * 12 + 4]);
        xn0 += qa0.x*w[0] + qa0.y*w[1] + qa0.z*w[2] + qa0.w*w[3]
             + qa1.x*w[4] + qa1.y*w[5] + qa1.z*w[6] + qa1.w*w[7];
        xn1 += qb0.x*w[0] + qb0.y*w[1] + qb0.z*w[2] + qb0.w*w[3]
             + qb1.x*w[4] + qb1.y*w[5] + qb1.z*w[6] + qb1.w*w[7];
    }
#pragma unroll
    for (int q = 0; q < 4; ++q) {
        const float4 F0 = *reinterpret_cast<const float4*>(&phiS[i * 20 + 4 * q]);
        const float4 F1 = *reinterpret_cast<const float4*>(&phiS[(i + 8) * 20 + 4 * q]);
        xn0 += F0.x*tv[4*q+0] + F0.y*tv[4*q+1] + F0.z*tv[4*q+2] + F0.w*tv[4*q+3];
        xn1 += F1.x*tv[4*q+0] + F1.y*tv[4*q+1] + F1.z*tv[4*q+2] + F1.w*tv[4*q+3];
    }

    // ---- gather x_new, out[b][i] = C[i,:] @ x_new ----
    float xv[16];
#pragma unroll
    for (int j = 0; j < 8; ++j) {
        xv[j]     = __shfl(xn0, j, 8);
        xv[j + 8] = __shfl(xn1, j, 8);
    }
    float o = 0.f;
#pragma unroll
    for (int q = 0; q < 4; ++q) {
        const float4 A = *reinterpret_cast<const float4*>(&CsS[i * 20 + 4 * q]);
        o += A.x*xv[4*q+0] + A.y*xv[4*q+1] + A.z*xv[4*q+2] + A.w*xv[4*q+3];
    }
    if (valid) out[b * 8 + i] = o;
}

extern "C" void kernel_launch(void* const* d_in, const int* in_sizes, int n_in,
                              void* d_out, int out_size, void* d_ws, size_t ws_size,
                              hipStream_t stream)
{
    const float* z   = (const float*)d_in[0];
    const float* x0  = (const float*)d_in[1];
    const float* P0  = (const float*)d_in[2];
    const float* phi = (const float*)d_in[3];
    const float* H   = (const float*)d_in[4];
    const float* C   = (const float*)d_in[5];
    const float* Qd  = (const float*)d_in[6];
    const float* Rd  = (const float*)d_in[7];
    float* out = (float*)d_out;

    const int bs = in_sizes[0] / 8;          // z is [bs, 8]
    const int blocks = (bs + 31) / 32;       // 32 elements per block
    hipLaunchKernelGGL(kalman_fused3, dim3(blocks), dim3(256), 0, stream,
                       z, x0, P0, phi, H, C, Qd, Rd, out, bs);
}